// Round 3
// baseline (2347.766 us; speedup 1.0000x reference)
//
#include <hip/hip_runtime.h>
#include <stdint.h>
#include <math.h>

static constexpr int B_   = 4;
static constexpr int N1   = 255780;   // total anchors per image across 5 levels
static constexpr int PRE  = 6000;
static constexpr int POST = 1000;
static constexpr int MWORDS = 94;     // ceil(6000/64)
static constexpr float NEGF = -1000000000.0f;

__device__ __constant__ int c_OFF[6] = {0,192000,240000,252000,255000,255780};
__device__ __constant__ int c_H[5]   = {200,100,50,25,13};
__device__ __constant__ int c_W[5]   = {320,160,80,40,20};
__device__ __constant__ int c_S[5]   = {4,8,16,32,64};

struct Ptrs { const float* cls[5]; const float* bbox[5]; };

// ---------- helpers ----------
__device__ __forceinline__ unsigned forder(float f) {
  unsigned u = __float_as_uint(f);
  return (u & 0x80000000u) ? ~u : (u | 0x80000000u);
}
__device__ __forceinline__ float funorder(unsigned u) {
  u = (u & 0x80000000u) ? (u & 0x7FFFFFFFu) : ~u;
  return __uint_as_float(u);
}

// descending bitonic sort of n (power of 2) 64-bit keys in LDS
__device__ __forceinline__ void bitonic_desc(unsigned long long* key, int n, int tid, int nt) {
  for (int k = 2; k <= n; k <<= 1) {
    for (int j = k >> 1; j > 0; j >>= 1) {
      __syncthreads();
      for (int i = tid; i < n; i += nt) {
        int l = i ^ j;
        if (l > i) {
          unsigned long long a = key[i], b = key[l];
          bool up = ((i & k) == 0);
          if ((a < b) == up) { key[i] = b; key[l] = a; }
        }
      }
    }
  }
  __syncthreads();
}

// base anchor (legacy +1 convention), double math == numpy float64, rint == np.round
__device__ __forceinline__ void anchor_for(int lvl, int a, float& ax1, float& ay1, float& ax2, float& ay2) {
  int st = c_S[lvl];
  double size = (double)st * (double)st;
  double c = 0.5 * (double)(st - 1);
  double r = (a == 0) ? 0.5 : (a == 1) ? 1.0 : 2.0;
  double ws = rint(sqrt(size / r));
  double hs = rint(ws * r);
  double w2 = ws * 8.0, h2 = hs * 8.0;
  ax1 = (float)(c - 0.5 * (w2 - 1.0));
  ay1 = (float)(c - 0.5 * (h2 - 1.0));
  ax2 = (float)(c + 0.5 * (w2 - 1.0));
  ay2 = (float)(c + 0.5 * (h2 - 1.0));
}

// decode one anchor exactly as the reference (per-op f32 rounding, no FMA)
__device__ __forceinline__ void decode_one(const Ptrs& P, int b, int gi, float wlim, float hlim,
                                           float& x1, float& y1, float& x2, float& y2, bool& valid) {
  int lvl = (gi >= c_OFF[4]) ? 4 : (gi >= c_OFF[3]) ? 3 : (gi >= c_OFF[2]) ? 2 : (gi >= c_OFF[1]) ? 1 : 0;
  int rem = gi - c_OFF[lvl];
  int a = rem % 3;
  int pos = rem / 3;
  int W = c_W[lvl];
  int h = pos / W, w = pos - h * W;
  size_t hw = (size_t)c_H[lvl] * W;
  const float* bb = P.bbox[lvl] + ((size_t)b * 12 + 4 * a) * hw + (size_t)h * W + w;
  float d0 = bb[0], d1 = bb[hw], d2 = bb[2 * hw], d3 = bb[3 * hw];

  float ax1, ay1, ax2, ay2;
  anchor_for(lvl, a, ax1, ay1, ax2, ay2);
  int st = c_S[lvl];
  float sx = (float)(w * st), sy = (float)(h * st);
  ax1 += sx; ax2 += sx; ay1 += sy; ay2 += sy;   // exact integers

  float aw  = __fadd_rn(__fsub_rn(ax2, ax1), 1.0f);
  float ah  = __fadd_rn(__fsub_rn(ay2, ay1), 1.0f);
  float acx = __fadd_rn(ax1, __fmul_rn(0.5f, __fsub_rn(aw, 1.0f)));
  float acy = __fadd_rn(ay1, __fmul_rn(0.5f, __fsub_rn(ah, 1.0f)));
  float ew  = (float)exp((double)d2);
  float eh  = (float)exp((double)d3);
  float pcx = __fadd_rn(__fmul_rn(d0, aw), acx);
  float pcy = __fadd_rn(__fmul_rn(d1, ah), acy);
  float pw  = __fmul_rn(ew, aw);
  float ph  = __fmul_rn(eh, ah);
  float hwf = __fmul_rn(0.5f, __fsub_rn(pw, 1.0f));
  float hhf = __fmul_rn(0.5f, __fsub_rn(ph, 1.0f));
  x1 = __fsub_rn(pcx, hwf);
  x2 = __fadd_rn(pcx, hwf);
  y1 = __fsub_rn(pcy, hhf);
  y2 = __fadd_rn(pcy, hhf);
  x1 = fminf(fmaxf(x1, 0.0f), wlim);
  x2 = fminf(fmaxf(x2, 0.0f), wlim);
  y1 = fminf(fmaxf(y1, 0.0f), hlim);
  y2 = fminf(fmaxf(y2, 0.0f), hlim);
  valid = (__fadd_rn(__fsub_rn(x2, x1), 1.0f) >= 0.0f) &&
          (__fadd_rn(__fsub_rn(y2, y1), 1.0f) >= 0.0f);
}

// ---------- kernel A: masked scores for every anchor ----------
__global__ void k_scores(Ptrs P, const float* im_info, float* scores) {
  int i = blockIdx.x * blockDim.x + threadIdx.x;
  int b = blockIdx.y;
  if (i >= N1) return;
  float wlim = __fsub_rn(im_info[b * 3 + 1], 1.0f);
  float hlim = __fsub_rn(im_info[b * 3 + 0], 1.0f);
  float x1, y1, x2, y2; bool valid;
  decode_one(P, b, i, wlim, hlim, x1, y1, x2, y2, valid);

  int lvl = (i >= c_OFF[4]) ? 4 : (i >= c_OFF[3]) ? 3 : (i >= c_OFF[2]) ? 2 : (i >= c_OFF[1]) ? 1 : 0;
  int rem = i - c_OFF[lvl];
  int a = rem % 3;
  int pos = rem / 3;
  int W = c_W[lvl];
  int h = pos / W, w = pos - h * W;
  size_t hw = (size_t)c_H[lvl] * W;
  float s = P.cls[lvl][((size_t)b * 6 + 3 + a) * hw + (size_t)h * W + w];
  scores[(size_t)b * N1 + i] = valid ? s : NEGF;
}

// ---------- kernel B: per-image top-6000 (sorted, stable) ----------
__global__ __launch_bounds__(1024) void k_select(const float* scores, int* selIdx, float* selScore) {
  int b = blockIdx.x, tid = threadIdx.x;
  __shared__ unsigned long long s_keys[8192];
  __shared__ int s_hist[4096];
  __shared__ int s_cut, s_cnt;
  const float* sc = scores + (size_t)b * N1;

  for (int i = tid; i < 4096; i += 1024) s_hist[i] = 0;
  for (int i = tid; i < 8192; i += 1024) s_keys[i] = 0;
  if (tid == 0) s_cnt = 0;
  __syncthreads();
  for (int i = tid; i < N1; i += 1024) {
    float s = sc[i];
    int bk = (int)(s * 4096.0f);
    bk = max(0, min(4095, bk));
    atomicAdd(&s_hist[bk], 1);
  }
  __syncthreads();
  if (tid == 0) {
    int cum = 0, cut = 0;
    for (int k = 4095; k >= 0; --k) { cum += s_hist[k]; if (cum >= PRE) { cut = k; break; } }
    s_cut = cut;
  }
  __syncthreads();
  int cut = s_cut;
  for (int i = tid; i < N1; i += 1024) {
    float s = sc[i];
    int bk = (int)(s * 4096.0f);
    bk = max(0, min(4095, bk));
    if (bk >= cut) {
      int p = atomicAdd(&s_cnt, 1);
      if (p < 8192)
        s_keys[p] = ((unsigned long long)forder(s) << 32) |
                    (unsigned long long)(0xFFFFFFFFu - (unsigned)i);
    }
  }
  __syncthreads();
  bitonic_desc(s_keys, 8192, tid, 1024);
  for (int r = tid; r < PRE; r += 1024) {
    unsigned long long k = s_keys[r];
    unsigned idx = 0xFFFFFFFFu - (unsigned)(k & 0xFFFFFFFFull);
    selIdx[(size_t)b * PRE + r]   = (int)idx;
    selScore[(size_t)b * PRE + r] = funorder((unsigned)(k >> 32));
  }
}

// ---------- kernel C: decode the selected 6000 boxes per image ----------
__global__ void k_decode(Ptrs P, const float* im_info, const int* selIdx, float* boxes) {
  int r = blockIdx.x * blockDim.x + threadIdx.x;
  int b = blockIdx.y;
  if (r >= PRE) return;
  float wlim = __fsub_rn(im_info[b * 3 + 1], 1.0f);
  float hlim = __fsub_rn(im_info[b * 3 + 0], 1.0f);
  int gi = selIdx[(size_t)b * PRE + r];
  float x1, y1, x2, y2; bool valid;
  decode_one(P, b, gi, wlim, hlim, x1, y1, x2, y2, valid);
  float* o = boxes + ((size_t)b * PRE + r) * 4;
  o[0] = x1; o[1] = y1; o[2] = x2; o[3] = y2;
}

// ---------- kernel D: IoU suppression bitmasks (zero-filled lower triangle) ----------
__global__ void k_mask(const float* boxes, unsigned long long* mask) {
  int cb = blockIdx.x, rb = blockIdx.y, b = blockIdx.z;
  int t = threadIdx.x;  // 64 threads
  __shared__ float cx1[64], cy1[64], cx2[64], cy2[64], car[64];
  int j0 = cb * 64;
  int jn = min(64, PRE - j0);
  if (cb >= rb && t < jn) {
    const float* bj = boxes + ((size_t)b * PRE + j0 + t) * 4;
    float a1 = bj[0], b1 = bj[1], a2 = bj[2], b2 = bj[3];
    cx1[t] = a1; cy1[t] = b1; cx2[t] = a2; cy2[t] = b2;
    car[t] = __fmul_rn(__fadd_rn(__fsub_rn(a2, a1), 1.0f),
                       __fadd_rn(__fsub_rn(b2, b1), 1.0f));
  }
  __syncthreads();
  int i = rb * 64 + t;
  if (i >= PRE) return;
  unsigned long long bits = 0;
  if (cb >= rb) {
    const float* bi = boxes + ((size_t)b * PRE + i) * 4;
    float x1 = bi[0], y1 = bi[1], x2 = bi[2], y2 = bi[3];
    float ai = __fmul_rn(__fadd_rn(__fsub_rn(x2, x1), 1.0f),
                         __fadd_rn(__fsub_rn(y2, y1), 1.0f));
    for (int jj = 0; jj < jn; ++jj) {
      int j = j0 + jj;
      if (j <= i) continue;
      float xx1 = fmaxf(x1, cx1[jj]);
      float yy1 = fmaxf(y1, cy1[jj]);
      float xx2 = fminf(x2, cx2[jj]);
      float yy2 = fminf(y2, cy2[jj]);
      float ww = fmaxf(__fadd_rn(__fsub_rn(xx2, xx1), 1.0f), 0.0f);
      float hh = fmaxf(__fadd_rn(__fsub_rn(yy2, yy1), 1.0f), 0.0f);
      float inter = __fmul_rn(ww, hh);
      float uni = __fsub_rn(__fadd_rn(ai, car[jj]), inter);
      float iou = __fdiv_rn(inter, uni);
      if (iou > 0.7f) bits |= (1ull << jj);
    }
  }
  mask[((size_t)b * PRE + i) * MWORDS + cb] = bits;
}

// ---------- kernel E: greedy scan — block-decomposed (serial part register-only) ----------
// Per 64-row block rb:
//   Phase 1: aliveness of the 64 rows needs only the running word rb (2 readlanes)
//            and the 64 diagonal words (1 load/lane, chain-independent). Serial
//            chain is scalar bit-test -> mask -> or, ~4cy/row.
//   Phase 2: OR full rows of alive boxes into r0/r1, branchless (w & sel | acc).
//            Loads are unconditional => freely pipelined by the compiler.
__global__ __launch_bounds__(64, 1) void k_scan(const unsigned long long* __restrict__ mask,
                                                unsigned long long* __restrict__ rem) {
  const int b = blockIdx.x, lane = threadIdx.x;  // 64 threads
  const unsigned long long* m = mask + (size_t)b * PRE * MWORDS;
  const bool has2 = lane < (MWORDS - 64);   // lanes 0..29 own word 64+lane
  unsigned long long r0 = 0, r1 = 0;        // running suppression, words lane / 64+lane

  for (int rb = 0; rb < MWORDS; ++rb) {
    const int row0 = rb << 6;
    const int nrows = min(64, PRE - row0);

    // diagonal word of my row in this block (zero-padded)
    unsigned long long diag = (lane < nrows) ? m[(size_t)(row0 + lane) * MWORDS + rb] : 0ull;

    // current suppression word rb (uniform)
    unsigned slo, shi;
    if (rb < 64) {
      slo = __builtin_amdgcn_readlane((unsigned)r0, rb);
      shi = __builtin_amdgcn_readlane((unsigned)(r0 >> 32), rb);
    } else {
      slo = __builtin_amdgcn_readlane((unsigned)r1, rb - 64);
      shi = __builtin_amdgcn_readlane((unsigned)(r1 >> 32), rb - 64);
    }
    unsigned long long state = ((unsigned long long)shi << 32) | slo;

    // phase 1: serial aliveness (scalar chain; readlanes are off-chain)
    unsigned long long alive = 0;
    #pragma unroll 8
    for (int kk = 0; kk < nrows; ++kk) {
      unsigned dlo = __builtin_amdgcn_readlane((unsigned)diag, kk);
      unsigned dhi = __builtin_amdgcn_readlane((unsigned)(diag >> 32), kk);
      unsigned long long d = ((unsigned long long)dhi << 32) | dlo;
      unsigned long long a = ((state >> kk) & 1ull) ^ 1ull;   // 1 if alive
      unsigned long long amask = 0ull - a;
      alive |= a << kk;
      state |= d & amask;
    }

    // phase 2: branchless OR of alive rows (unconditional loads; lower-tri words are 0)
    #pragma unroll 4
    for (int kk = 0; kk < nrows; ++kk) {
      unsigned long long sel = 0ull - ((alive >> kk) & 1ull);
      const unsigned long long* row = m + (size_t)(row0 + kk) * MWORDS;
      unsigned long long w0 = (lane >= rb) ? row[lane] : 0ull;
      r0 |= w0 & sel;
      if (has2) {
        unsigned long long w1 = (64 + lane >= rb) ? row[64 + lane] : 0ull;
        r1 |= w1 & sel;
      }
    }
  }

  rem[b * 128 + lane] = r0;
  if (has2) rem[b * 128 + 64 + lane] = r1;
}

// ---------- kernel F: per-image post-NMS top-1000 (sorted) ----------
__global__ __launch_bounds__(1024) void k_post(const float* selScore, const unsigned long long* rem,
                                               unsigned long long* pk) {
  int b = blockIdx.x, tid = threadIdx.x;
  __shared__ unsigned long long s_keys[8192];
  const unsigned long long* rw = rem + b * 128;
  for (int i = tid; i < 8192; i += 1024) {
    unsigned long long key = 0;
    if (i < PRE) {
      bool suppressed = (rw[i >> 6] >> (i & 63)) & 1ull;
      float s = suppressed ? NEGF : selScore[(size_t)b * PRE + i];
      unsigned tiev = 0xFFFFFFFFu - (unsigned)(b * 8192 + i);
      key = ((unsigned long long)forder(s) << 32) | (unsigned long long)tiev;
    }
    s_keys[i] = key;
  }
  __syncthreads();
  bitonic_desc(s_keys, 8192, tid, 1024);
  for (int r = tid; r < POST; r += 1024) pk[(size_t)b * POST + r] = s_keys[r];
}

// ---------- kernel G: global top-1000 of the 4000 + gather output ----------
__global__ __launch_bounds__(1024) void k_final(const unsigned long long* pk, const float* boxes,
                                                float* out) {
  int tid = threadIdx.x;
  __shared__ unsigned long long s_keys[4096];
  for (int i = tid; i < 4096; i += 1024) s_keys[i] = (i < B_ * POST) ? pk[i] : 0ull;
  __syncthreads();
  bitonic_desc(s_keys, 4096, tid, 1024);
  for (int r = tid; r < POST; r += 1024) {
    unsigned long long k = s_keys[r];
    unsigned v = 0xFFFFFFFFu - (unsigned)(k & 0xFFFFFFFFull);
    int b = v >> 13, pos = v & 8191;
    float s = funorder((unsigned)(k >> 32));
    const float* bx = boxes + ((size_t)b * PRE + pos) * 4;
    out[r * 5 + 0] = (float)b;
    out[r * 5 + 1] = bx[0];
    out[r * 5 + 2] = bx[1];
    out[r * 5 + 3] = bx[2];
    out[r * 5 + 4] = bx[3];
    out[5 * POST + r] = s;
  }
}

// ---------- workspace layout (bytes, all 8-aligned) ----------
static constexpr size_t OFF_SC   = 0;                                  // B*N1 f32
static constexpr size_t OFF_SELS = OFF_SC   + (size_t)B_ * N1 * 4;     // B*PRE f32
static constexpr size_t OFF_SELI = OFF_SELS + (size_t)B_ * PRE * 4;    // B*PRE i32
static constexpr size_t OFF_BOX  = OFF_SELI + (size_t)B_ * PRE * 4;    // B*PRE*4 f32
static constexpr size_t OFF_MASK = OFF_BOX  + (size_t)B_ * PRE * 16;   // B*PRE*94 u64
static constexpr size_t OFF_REM  = OFF_MASK + (size_t)B_ * PRE * MWORDS * 8; // B*128 u64
static constexpr size_t OFF_PK   = OFF_REM  + (size_t)B_ * 128 * 8;    // B*POST u64

extern "C" void kernel_launch(void* const* d_in, const int* in_sizes, int n_in,
                              void* d_out, int out_size, void* d_ws, size_t ws_size,
                              hipStream_t stream) {
  Ptrs P;
  // setup_inputs() dict order is interleaved (cls_p2, bbox_p2, ...); detect defensively.
  bool interleaved = (n_in >= 2) && (in_sizes[1] == 2 * in_sizes[0]);
  for (int l = 0; l < 5; ++l) {
    if (interleaved) { P.cls[l] = (const float*)d_in[2 * l]; P.bbox[l] = (const float*)d_in[2 * l + 1]; }
    else             { P.cls[l] = (const float*)d_in[l];     P.bbox[l] = (const float*)d_in[5 + l]; }
  }
  const float* im_info = (const float*)d_in[10];

  char* ws = (char*)d_ws;
  float*              scores   = (float*)(ws + OFF_SC);
  float*              selScore = (float*)(ws + OFF_SELS);
  int*                selIdx   = (int*)(ws + OFF_SELI);
  float*              selBoxes = (float*)(ws + OFF_BOX);
  unsigned long long* maskBuf  = (unsigned long long*)(ws + OFF_MASK);
  unsigned long long* remBuf   = (unsigned long long*)(ws + OFF_REM);
  unsigned long long* postKeys = (unsigned long long*)(ws + OFF_PK);
  float*              out      = (float*)d_out;

  k_scores<<<dim3((N1 + 255) / 256, B_), 256, 0, stream>>>(P, im_info, scores);
  k_select<<<B_, 1024, 0, stream>>>(scores, selIdx, selScore);
  k_decode<<<dim3((PRE + 255) / 256, B_), 256, 0, stream>>>(P, im_info, selIdx, selBoxes);
  k_mask<<<dim3(MWORDS, MWORDS, B_), 64, 0, stream>>>(selBoxes, maskBuf);
  k_scan<<<B_, 64, 0, stream>>>(maskBuf, remBuf);
  k_post<<<B_, 1024, 0, stream>>>(selScore, remBuf, postKeys);
  k_final<<<1, 1024, 0, stream>>>(postKeys, selBoxes, out);
}

// Round 4
// 706.449 us; speedup vs baseline: 3.3233x; 3.3233x over previous
//
#include <hip/hip_runtime.h>
#include <stdint.h>
#include <math.h>

static constexpr int B_   = 4;
static constexpr int N1   = 255780;   // total anchors per image across 5 levels
static constexpr int PRE  = 6000;
static constexpr int POST = 1000;
static constexpr int MWORDS = 94;     // ceil(6000/64)
static constexpr float NEGF = -1000000000.0f;

__device__ __constant__ int c_OFF[6] = {0,192000,240000,252000,255000,255780};
__device__ __constant__ int c_H[5]   = {200,100,50,25,13};
__device__ __constant__ int c_W[5]   = {320,160,80,40,20};
__device__ __constant__ int c_S[5]   = {4,8,16,32,64};

struct Ptrs { const float* cls[5]; const float* bbox[5]; };

// ---------- helpers ----------
__device__ __forceinline__ unsigned forder(float f) {
  unsigned u = __float_as_uint(f);
  return (u & 0x80000000u) ? ~u : (u | 0x80000000u);
}
__device__ __forceinline__ float funorder(unsigned u) {
  u = (u & 0x80000000u) ? (u & 0x7FFFFFFFu) : ~u;
  return __uint_as_float(u);
}

// descending bitonic sort of n (power of 2) 64-bit keys in LDS
__device__ __forceinline__ void bitonic_desc(unsigned long long* key, int n, int tid, int nt) {
  for (int k = 2; k <= n; k <<= 1) {
    for (int j = k >> 1; j > 0; j >>= 1) {
      __syncthreads();
      for (int i = tid; i < n; i += nt) {
        int l = i ^ j;
        if (l > i) {
          unsigned long long a = key[i], b = key[l];
          bool up = ((i & k) == 0);
          if ((a < b) == up) { key[i] = b; key[l] = a; }
        }
      }
    }
  }
  __syncthreads();
}

// base anchor (legacy +1 convention), double math == numpy float64, rint == np.round
__device__ __forceinline__ void anchor_for(int lvl, int a, float& ax1, float& ay1, float& ax2, float& ay2) {
  int st = c_S[lvl];
  double size = (double)st * (double)st;
  double c = 0.5 * (double)(st - 1);
  double r = (a == 0) ? 0.5 : (a == 1) ? 1.0 : 2.0;
  double ws = rint(sqrt(size / r));
  double hs = rint(ws * r);
  double w2 = ws * 8.0, h2 = hs * 8.0;
  ax1 = (float)(c - 0.5 * (w2 - 1.0));
  ay1 = (float)(c - 0.5 * (h2 - 1.0));
  ax2 = (float)(c + 0.5 * (w2 - 1.0));
  ay2 = (float)(c + 0.5 * (h2 - 1.0));
}

// decode one anchor exactly as the reference (per-op f32 rounding, no FMA)
__device__ __forceinline__ void decode_one(const Ptrs& P, int b, int gi, float wlim, float hlim,
                                           float& x1, float& y1, float& x2, float& y2, bool& valid) {
  int lvl = (gi >= c_OFF[4]) ? 4 : (gi >= c_OFF[3]) ? 3 : (gi >= c_OFF[2]) ? 2 : (gi >= c_OFF[1]) ? 1 : 0;
  int rem = gi - c_OFF[lvl];
  int a = rem % 3;
  int pos = rem / 3;
  int W = c_W[lvl];
  int h = pos / W, w = pos - h * W;
  size_t hw = (size_t)c_H[lvl] * W;
  const float* bb = P.bbox[lvl] + ((size_t)b * 12 + 4 * a) * hw + (size_t)h * W + w;
  float d0 = bb[0], d1 = bb[hw], d2 = bb[2 * hw], d3 = bb[3 * hw];

  float ax1, ay1, ax2, ay2;
  anchor_for(lvl, a, ax1, ay1, ax2, ay2);
  int st = c_S[lvl];
  float sx = (float)(w * st), sy = (float)(h * st);
  ax1 += sx; ax2 += sx; ay1 += sy; ay2 += sy;   // exact integers

  float aw  = __fadd_rn(__fsub_rn(ax2, ax1), 1.0f);
  float ah  = __fadd_rn(__fsub_rn(ay2, ay1), 1.0f);
  float acx = __fadd_rn(ax1, __fmul_rn(0.5f, __fsub_rn(aw, 1.0f)));
  float acy = __fadd_rn(ay1, __fmul_rn(0.5f, __fsub_rn(ah, 1.0f)));
  float ew  = (float)exp((double)d2);
  float eh  = (float)exp((double)d3);
  float pcx = __fadd_rn(__fmul_rn(d0, aw), acx);
  float pcy = __fadd_rn(__fmul_rn(d1, ah), acy);
  float pw  = __fmul_rn(ew, aw);
  float ph  = __fmul_rn(eh, ah);
  float hwf = __fmul_rn(0.5f, __fsub_rn(pw, 1.0f));
  float hhf = __fmul_rn(0.5f, __fsub_rn(ph, 1.0f));
  x1 = __fsub_rn(pcx, hwf);
  x2 = __fadd_rn(pcx, hwf);
  y1 = __fsub_rn(pcy, hhf);
  y2 = __fadd_rn(pcy, hhf);
  x1 = fminf(fmaxf(x1, 0.0f), wlim);
  x2 = fminf(fmaxf(x2, 0.0f), wlim);
  y1 = fminf(fmaxf(y1, 0.0f), hlim);
  y2 = fminf(fmaxf(y2, 0.0f), hlim);
  valid = (__fadd_rn(__fsub_rn(x2, x1), 1.0f) >= 0.0f) &&
          (__fadd_rn(__fsub_rn(y2, y1), 1.0f) >= 0.0f);
}

// ---------- kernel A: masked scores for every anchor ----------
__global__ void k_scores(Ptrs P, const float* im_info, float* scores) {
  int i = blockIdx.x * blockDim.x + threadIdx.x;
  int b = blockIdx.y;
  if (i >= N1) return;
  float wlim = __fsub_rn(im_info[b * 3 + 1], 1.0f);
  float hlim = __fsub_rn(im_info[b * 3 + 0], 1.0f);
  float x1, y1, x2, y2; bool valid;
  decode_one(P, b, i, wlim, hlim, x1, y1, x2, y2, valid);

  int lvl = (i >= c_OFF[4]) ? 4 : (i >= c_OFF[3]) ? 3 : (i >= c_OFF[2]) ? 2 : (i >= c_OFF[1]) ? 1 : 0;
  int rem = i - c_OFF[lvl];
  int a = rem % 3;
  int pos = rem / 3;
  int W = c_W[lvl];
  int h = pos / W, w = pos - h * W;
  size_t hw = (size_t)c_H[lvl] * W;
  float s = P.cls[lvl][((size_t)b * 6 + 3 + a) * hw + (size_t)h * W + w];
  scores[(size_t)b * N1 + i] = valid ? s : NEGF;
}

// ---------- kernel B: per-image top-6000 (sorted, stable) ----------
__global__ __launch_bounds__(1024) void k_select(const float* scores, int* selIdx, float* selScore) {
  int b = blockIdx.x, tid = threadIdx.x;
  __shared__ unsigned long long s_keys[8192];
  __shared__ int s_hist[4096];
  __shared__ int s_cut, s_cnt;
  const float* sc = scores + (size_t)b * N1;

  for (int i = tid; i < 4096; i += 1024) s_hist[i] = 0;
  for (int i = tid; i < 8192; i += 1024) s_keys[i] = 0;
  if (tid == 0) s_cnt = 0;
  __syncthreads();
  for (int i = tid; i < N1; i += 1024) {
    float s = sc[i];
    int bk = (int)(s * 4096.0f);
    bk = max(0, min(4095, bk));
    atomicAdd(&s_hist[bk], 1);
  }
  __syncthreads();
  if (tid == 0) {
    int cum = 0, cut = 0;
    for (int k = 4095; k >= 0; --k) { cum += s_hist[k]; if (cum >= PRE) { cut = k; break; } }
    s_cut = cut;
  }
  __syncthreads();
  int cut = s_cut;
  for (int i = tid; i < N1; i += 1024) {
    float s = sc[i];
    int bk = (int)(s * 4096.0f);
    bk = max(0, min(4095, bk));
    if (bk >= cut) {
      int p = atomicAdd(&s_cnt, 1);
      if (p < 8192)
        s_keys[p] = ((unsigned long long)forder(s) << 32) |
                    (unsigned long long)(0xFFFFFFFFu - (unsigned)i);
    }
  }
  __syncthreads();
  bitonic_desc(s_keys, 8192, tid, 1024);
  for (int r = tid; r < PRE; r += 1024) {
    unsigned long long k = s_keys[r];
    unsigned idx = 0xFFFFFFFFu - (unsigned)(k & 0xFFFFFFFFull);
    selIdx[(size_t)b * PRE + r]   = (int)idx;
    selScore[(size_t)b * PRE + r] = funorder((unsigned)(k >> 32));
  }
}

// ---------- kernel C: decode the selected 6000 boxes per image ----------
__global__ void k_decode(Ptrs P, const float* im_info, const int* selIdx, float* boxes) {
  int r = blockIdx.x * blockDim.x + threadIdx.x;
  int b = blockIdx.y;
  if (r >= PRE) return;
  float wlim = __fsub_rn(im_info[b * 3 + 1], 1.0f);
  float hlim = __fsub_rn(im_info[b * 3 + 0], 1.0f);
  int gi = selIdx[(size_t)b * PRE + r];
  float x1, y1, x2, y2; bool valid;
  decode_one(P, b, gi, wlim, hlim, x1, y1, x2, y2, valid);
  float* o = boxes + ((size_t)b * PRE + r) * 4;
  o[0] = x1; o[1] = y1; o[2] = x2; o[3] = y2;
}

// ---------- kernel D: IoU suppression bitmasks (zero-filled lower triangle) ----------
__global__ void k_mask(const float* boxes, unsigned long long* mask) {
  int cb = blockIdx.x, rb = blockIdx.y, b = blockIdx.z;
  int t = threadIdx.x;  // 64 threads
  __shared__ float cx1[64], cy1[64], cx2[64], cy2[64], car[64];
  int j0 = cb * 64;
  int jn = min(64, PRE - j0);
  if (cb >= rb && t < jn) {
    const float* bj = boxes + ((size_t)b * PRE + j0 + t) * 4;
    float a1 = bj[0], b1 = bj[1], a2 = bj[2], b2 = bj[3];
    cx1[t] = a1; cy1[t] = b1; cx2[t] = a2; cy2[t] = b2;
    car[t] = __fmul_rn(__fadd_rn(__fsub_rn(a2, a1), 1.0f),
                       __fadd_rn(__fsub_rn(b2, b1), 1.0f));
  }
  __syncthreads();
  int i = rb * 64 + t;
  if (i >= PRE) return;
  unsigned long long bits = 0;
  if (cb >= rb) {
    const float* bi = boxes + ((size_t)b * PRE + i) * 4;
    float x1 = bi[0], y1 = bi[1], x2 = bi[2], y2 = bi[3];
    float ai = __fmul_rn(__fadd_rn(__fsub_rn(x2, x1), 1.0f),
                         __fadd_rn(__fsub_rn(y2, y1), 1.0f));
    for (int jj = 0; jj < jn; ++jj) {
      int j = j0 + jj;
      if (j <= i) continue;
      float xx1 = fmaxf(x1, cx1[jj]);
      float yy1 = fmaxf(y1, cy1[jj]);
      float xx2 = fminf(x2, cx2[jj]);
      float yy2 = fminf(y2, cy2[jj]);
      float ww = fmaxf(__fadd_rn(__fsub_rn(xx2, xx1), 1.0f), 0.0f);
      float hh = fmaxf(__fadd_rn(__fsub_rn(yy2, yy1), 1.0f), 0.0f);
      float inter = __fmul_rn(ww, hh);
      float uni = __fsub_rn(__fadd_rn(ai, car[jj]), inter);
      float iou = __fdiv_rn(inter, uni);
      if (iou > 0.7f) bits |= (1ull << jj);
    }
  }
  mask[((size_t)b * PRE + i) * MWORDS + cb] = bits;
}

// ---------- kernel E: greedy scan — 16-wave TLP version ----------
// One 1024-thread block per image. Per 64-row block rb:
//   phase 1 (wave 0): serial aliveness from LDS-resident diag tile + s_rem[rb].
//   phase 2 (752 threads = 8 row-splits x 94 columns): branchless masked OR of
//     the block's mask rows into s_rem via LDS atomicOr. Tile loads for block
//     rb+1 are issued before the barrier (independent of the serial state), so
//     L2 latency is hidden by prefetch + 16-way wave TLP, not by regalloc.
__global__ __launch_bounds__(1024, 1) void k_scan(const unsigned long long* __restrict__ mask,
                                                  unsigned long long* __restrict__ rem) {
  const int b = blockIdx.x, tid = threadIdx.x;
  const unsigned long long* m = mask + (size_t)b * PRE * MWORDS;

  __shared__ unsigned long long s_diag[MWORDS * 64];  // 48 KB
  __shared__ unsigned long long s_rem[MWORDS];
  __shared__ unsigned long long s_alive;

  for (int i = tid; i < MWORDS * 64; i += 1024) {
    int rb = i >> 6, l = i & 63;
    int row = (rb << 6) + l;
    s_diag[i] = (row < PRE) ? m[(size_t)row * MWORDS + rb] : 0ull;
  }
  for (int i = tid; i < MWORDS; i += 1024) s_rem[i] = 0ull;
  __syncthreads();

  const int j  = tid % MWORDS;   // column word
  const int sp = tid / MWORDS;   // row split
  const bool active = sp < 8;

  unsigned long long cur[8] = {0,0,0,0,0,0,0,0}, nxt[8] = {0,0,0,0,0,0,0,0};

#define LOADTILE(BUF, RB)                                                      \
  if (active && (RB) < MWORDS && j >= (RB)) {                                  \
    _Pragma("unroll")                                                          \
    for (int t = 0; t < 8; ++t) {                                              \
      int row = ((RB) << 6) + sp * 8 + t;                                      \
      BUF[t] = (row < PRE) ? m[(size_t)row * MWORDS + j] : 0ull;               \
    }                                                                          \
  } else {                                                                     \
    _Pragma("unroll")                                                          \
    for (int t = 0; t < 8; ++t) BUF[t] = 0ull;                                 \
  }

  LOADTILE(cur, 0)
  for (int rb = 0; rb < MWORDS; ++rb) {
    LOADTILE(nxt, rb + 1)          // prefetch next tile (state-independent)

    if (tid < 64) {                // phase 1: serial aliveness on wave 0
      unsigned long long diag  = s_diag[(rb << 6) + tid];
      unsigned long long state = s_rem[rb];
      unsigned long long alive = 0;
      #pragma unroll
      for (int kk = 0; kk < 64; ++kk) {
        unsigned dlo = __builtin_amdgcn_readlane((unsigned)diag, kk);
        unsigned dhi = __builtin_amdgcn_readlane((unsigned)(diag >> 32), kk);
        unsigned long long d = ((unsigned long long)dhi << 32) | dlo;
        unsigned long long a = ((state >> kk) & 1ull) ^ 1ull;   // 1 if alive
        alive |= a << kk;
        state |= d & (0ull - a);
      }
      if (tid == 0) { s_rem[rb] = state; s_alive = alive; }
    }
    __syncthreads();

    if (active) {                  // phase 2: branchless masked OR
      unsigned long long alive = s_alive;
      unsigned long long acc = 0;
      #pragma unroll
      for (int t = 0; t < 8; ++t) {
        unsigned long long selm = 0ull - ((alive >> (sp * 8 + t)) & 1ull);
        acc |= cur[t] & selm;
      }
      if (acc) atomicOr(&s_rem[j], acc);
      #pragma unroll
      for (int t = 0; t < 8; ++t) cur[t] = nxt[t];
    }
    __syncthreads();
  }
#undef LOADTILE

  for (int i = tid; i < 128; i += 1024)
    rem[b * 128 + i] = (i < MWORDS) ? s_rem[i] : 0ull;
}

// ---------- kernel F: per-image post-NMS top-1000 (sorted) ----------
__global__ __launch_bounds__(1024) void k_post(const float* selScore, const unsigned long long* rem,
                                               unsigned long long* pk) {
  int b = blockIdx.x, tid = threadIdx.x;
  __shared__ unsigned long long s_keys[8192];
  const unsigned long long* rw = rem + b * 128;
  for (int i = tid; i < 8192; i += 1024) {
    unsigned long long key = 0;
    if (i < PRE) {
      bool suppressed = (rw[i >> 6] >> (i & 63)) & 1ull;
      float s = suppressed ? NEGF : selScore[(size_t)b * PRE + i];
      unsigned tiev = 0xFFFFFFFFu - (unsigned)(b * 8192 + i);
      key = ((unsigned long long)forder(s) << 32) | (unsigned long long)tiev;
    }
    s_keys[i] = key;
  }
  __syncthreads();
  bitonic_desc(s_keys, 8192, tid, 1024);
  for (int r = tid; r < POST; r += 1024) pk[(size_t)b * POST + r] = s_keys[r];
}

// ---------- kernel G: global top-1000 of the 4000 + gather output ----------
__global__ __launch_bounds__(1024) void k_final(const unsigned long long* pk, const float* boxes,
                                                float* out) {
  int tid = threadIdx.x;
  __shared__ unsigned long long s_keys[4096];
  for (int i = tid; i < 4096; i += 1024) s_keys[i] = (i < B_ * POST) ? pk[i] : 0ull;
  __syncthreads();
  bitonic_desc(s_keys, 4096, tid, 1024);
  for (int r = tid; r < POST; r += 1024) {
    unsigned long long k = s_keys[r];
    unsigned v = 0xFFFFFFFFu - (unsigned)(k & 0xFFFFFFFFull);
    int b = v >> 13, pos = v & 8191;
    float s = funorder((unsigned)(k >> 32));
    const float* bx = boxes + ((size_t)b * PRE + pos) * 4;
    out[r * 5 + 0] = (float)b;
    out[r * 5 + 1] = bx[0];
    out[r * 5 + 2] = bx[1];
    out[r * 5 + 3] = bx[2];
    out[r * 5 + 4] = bx[3];
    out[5 * POST + r] = s;
  }
}

// ---------- workspace layout (bytes, all 8-aligned) ----------
static constexpr size_t OFF_SC   = 0;                                  // B*N1 f32
static constexpr size_t OFF_SELS = OFF_SC   + (size_t)B_ * N1 * 4;     // B*PRE f32
static constexpr size_t OFF_SELI = OFF_SELS + (size_t)B_ * PRE * 4;    // B*PRE i32
static constexpr size_t OFF_BOX  = OFF_SELI + (size_t)B_ * PRE * 4;    // B*PRE*4 f32
static constexpr size_t OFF_MASK = OFF_BOX  + (size_t)B_ * PRE * 16;   // B*PRE*94 u64
static constexpr size_t OFF_REM  = OFF_MASK + (size_t)B_ * PRE * MWORDS * 8; // B*128 u64
static constexpr size_t OFF_PK   = OFF_REM  + (size_t)B_ * 128 * 8;    // B*POST u64

extern "C" void kernel_launch(void* const* d_in, const int* in_sizes, int n_in,
                              void* d_out, int out_size, void* d_ws, size_t ws_size,
                              hipStream_t stream) {
  Ptrs P;
  // setup_inputs() dict order is interleaved (cls_p2, bbox_p2, ...); detect defensively.
  bool interleaved = (n_in >= 2) && (in_sizes[1] == 2 * in_sizes[0]);
  for (int l = 0; l < 5; ++l) {
    if (interleaved) { P.cls[l] = (const float*)d_in[2 * l]; P.bbox[l] = (const float*)d_in[2 * l + 1]; }
    else             { P.cls[l] = (const float*)d_in[l];     P.bbox[l] = (const float*)d_in[5 + l]; }
  }
  const float* im_info = (const float*)d_in[10];

  char* ws = (char*)d_ws;
  float*              scores   = (float*)(ws + OFF_SC);
  float*              selScore = (float*)(ws + OFF_SELS);
  int*                selIdx   = (int*)(ws + OFF_SELI);
  float*              selBoxes = (float*)(ws + OFF_BOX);
  unsigned long long* maskBuf  = (unsigned long long*)(ws + OFF_MASK);
  unsigned long long* remBuf   = (unsigned long long*)(ws + OFF_REM);
  unsigned long long* postKeys = (unsigned long long*)(ws + OFF_PK);
  float*              out      = (float*)d_out;

  k_scores<<<dim3((N1 + 255) / 256, B_), 256, 0, stream>>>(P, im_info, scores);
  k_select<<<B_, 1024, 0, stream>>>(scores, selIdx, selScore);
  k_decode<<<dim3((PRE + 255) / 256, B_), 256, 0, stream>>>(P, im_info, selIdx, selBoxes);
  k_mask<<<dim3(MWORDS, MWORDS, B_), 64, 0, stream>>>(selBoxes, maskBuf);
  k_scan<<<B_, 1024, 0, stream>>>(maskBuf, remBuf);
  k_post<<<B_, 1024, 0, stream>>>(selScore, remBuf, postKeys);
  k_final<<<1, 1024, 0, stream>>>(postKeys, selBoxes, out);
}